// Round 12
// baseline (163.392 us; speedup 1.0000x reference)
//
#include <hip/hip_runtime.h>
#include <hip/hip_bf16.h>
#include <math.h>

// Problem constants (match reference setup_inputs)
#define T_N   400      // NTHETA
#define K_PAD 416      // 13 * 32 (MFMA K-steps), padded with zero kern
#define Z_N   128      // NZ
#define XY_N  16384    // NX*NY
#define NCPLX (3 * XY_N * Z_N)          // 6291456 = confirmed out_size (f32, real part)
#define A_CONST 5.905249382768714f      // pi / 0.532

typedef short  bf16x8 __attribute__((ext_vector_type(8)));
typedef float  f32x4  __attribute__((ext_vector_type(4)));

static __device__ __forceinline__ short f2bf(float f) {
    __hip_bfloat16 h = __float2bfloat16(f);
    return *reinterpret_cast<short*>(&h);
}
static __device__ __forceinline__ bf16x8 cvt8(float4 lo, float4 hi) {
    bf16x8 a;
    a[0] = f2bf(lo.x); a[1] = f2bf(lo.y); a[2] = f2bf(lo.z); a[3] = f2bf(lo.w);
    a[4] = f2bf(hi.x); a[5] = f2bf(hi.y); a[6] = f2bf(hi.z); a[7] = f2bf(hi.w);
    return a;
}

// ---------------------------------------------------------------------------
// Build B in ws: kernBT[p][z][k] bf16; p=0: w*cos(ang), p=1: w*sin(ang),
// ang = abbr[k] - U[z]*cos(theta[k]); k in [400,416) -> 0 (zero-pad).
// ---------------------------------------------------------------------------
__global__ __launch_bounds__(256) void kern_build_bf16(
    const float* __restrict__ abbr,
    const float* __restrict__ theta,
    const float* __restrict__ U,
    __hip_bfloat16* __restrict__ kernBT)
{
    int idx = blockIdx.x * 256 + threadIdx.x;    // (p*128 + z)*K_PAD + k
    if (idx >= 2 * Z_N * K_PAD) return;
    int k  = idx % K_PAD;
    int pz = idx / K_PAD;
    int z  = pz & 127;
    int p  = pz >> 7;

    float val = 0.f;
    if (k < T_N) {
        float th = theta[k];
        float w;
        if (k == 0)            w = 0.5f * (theta[1] - theta[0]);
        else if (k == T_N - 1) w = 0.5f * (theta[T_N - 1] - theta[T_N - 2]);
        else                   w = 0.5f * (theta[k + 1] - theta[k - 1]);
        float ang = abbr[k] - U[z] * cosf(th);
        val = w * ((p == 0) ? cosf(ang) : sinf(ang));
    }
    kernBT[idx] = __float2bfloat16(val);
}

// ---------------------------------------------------------------------------
// MFMA main v2 (R9 post-mortem: was latency-bound at 2 waves/SIMD).
// Block = 16 rows x 128 z; wave w takes z-quarter zb = w*32. 1024 blocks ->
// 4096 waves = 4 waves/SIMD. Same-block waves read the same F rows -> L1/L2
// hits, HBM demand unchanged. Depth-1 A-prefetch (raw f32 during MFMA).
// A frag (16x16x32): lane l holds A[row=l&15][kb + (l>>4)*8 + 0..7]
// B frag:            lane l holds B[kb + (l>>4)*8 + 0..7][col=l&15]
// C frag:            col(z)=l&15, row(xy)=(l>>4)*4 + reg
// ---------------------------------------------------------------------------
__global__ __launch_bounds__(256, 4) void psf_mfma(
    const float* __restrict__ F0,
    const float* __restrict__ F1,
    const float* __restrict__ F2,
    const float* __restrict__ Phi,
    const __hip_bfloat16* __restrict__ kernBT,
    float* __restrict__ out)
{
    const int tid  = threadIdx.x;
    const int l    = tid & 63;
    const int wave = tid >> 6;
    const int R    = blockIdx.x << 4;      // 16 rows per block
    const int zb   = wave << 5;            // 32 z per wave

    const int arow  = R + (l & 15);
    const int chunk = (l >> 4) << 3;       // 0,8,16,24
    const int zcol  = zb + (l & 15);

    const size_t rbase = (size_t)arow * T_N;
    const float* a0p = F0 + rbase;
    const float* a1p = F1 + rbase;
    const float* a2p = F2 + rbase;

    const __hip_bfloat16* b00 = kernBT + (size_t)(0 * Z_N + zcol +  0) * K_PAD + chunk; // re
    const __hip_bfloat16* b01 = kernBT + (size_t)(0 * Z_N + zcol + 16) * K_PAD + chunk;
    const __hip_bfloat16* b10 = kernBT + (size_t)(1 * Z_N + zcol +  0) * K_PAD + chunk; // im
    const __hip_bfloat16* b11 = kernBT + (size_t)(1 * Z_N + zcol + 16) * K_PAD + chunk;

    f32x4 acc[3][2];
#pragma unroll
    for (int c = 0; c < 3; ++c)
#pragma unroll
        for (int zt = 0; zt < 2; ++zt) acc[c][zt] = (f32x4){0.f, 0.f, 0.f, 0.f};

    // Prologue: load + convert A for ks=0 (chunk < 400 always here).
    bf16x8 a_cur0, a_cur1, a_cur2;
    {
        const int koff = chunk;
        a_cur0 = cvt8(*(const float4*)(a0p + koff), *(const float4*)(a0p + koff + 4));
        a_cur1 = cvt8(*(const float4*)(a1p + koff), *(const float4*)(a1p + koff + 4));
        a_cur2 = cvt8(*(const float4*)(a2p + koff), *(const float4*)(a2p + koff + 4));
    }

#pragma unroll 1
    for (int ks = 0; ks < 13; ++ks) {
        const int kb = ks * 32;

        // B loads for current ks (213 KB, L2-resident)
        bf16x8 f00 = *(const bf16x8*)(b00 + kb);
        bf16x8 f01 = *(const bf16x8*)(b01 + kb);
        bf16x8 f10 = *(const bf16x8*)(b10 + kb);
        bf16x8 f11 = *(const bf16x8*)(b11 + kb);

        // A prefetch for ks+1 (issued before MFMA; waits land after it)
        float4 lo0, hi0, lo1, hi1, lo2, hi2;
        if (ks < 12) {
            int koff = kb + 32 + chunk;
            if (koff >= T_N) koff = 0;          // tail clamp: B zero-pad kills it
            lo0 = *(const float4*)(a0p + koff); hi0 = *(const float4*)(a0p + koff + 4);
            lo1 = *(const float4*)(a1p + koff); hi1 = *(const float4*)(a1p + koff + 4);
            lo2 = *(const float4*)(a2p + koff); hi2 = *(const float4*)(a2p + koff + 4);
        }

        // comp0 (F0 x im), comp1 (F1 x re), comp2 (F2 x im)
        acc[0][0] = __builtin_amdgcn_mfma_f32_16x16x32_bf16(a_cur0, f10, acc[0][0], 0, 0, 0);
        acc[0][1] = __builtin_amdgcn_mfma_f32_16x16x32_bf16(a_cur0, f11, acc[0][1], 0, 0, 0);
        acc[1][0] = __builtin_amdgcn_mfma_f32_16x16x32_bf16(a_cur1, f00, acc[1][0], 0, 0, 0);
        acc[1][1] = __builtin_amdgcn_mfma_f32_16x16x32_bf16(a_cur1, f01, acc[1][1], 0, 0, 0);
        acc[2][0] = __builtin_amdgcn_mfma_f32_16x16x32_bf16(a_cur2, f10, acc[2][0], 0, 0, 0);
        acc[2][1] = __builtin_amdgcn_mfma_f32_16x16x32_bf16(a_cur2, f11, acc[2][1], 0, 0, 0);

        if (ks < 12) {
            a_cur0 = cvt8(lo0, hi0);
            a_cur1 = cvt8(lo1, hi1);
            a_cur2 = cvt8(lo2, hi2);
        }
    }

    // Epilogue: Re(Ex) = -A*(I0im + I2im*cos2p); Re(Ey) = -A*I2im*sin2p;
    //           Re(Ez) = -2A*I1re*cosp
    const int xyb = R + ((l >> 4) << 2);
#pragma unroll
    for (int r = 0; r < 4; ++r) {
        const int xy = xyb + r;
        float ph = Phi[xy];
        float sp, cp;
        sincosf(ph, &sp, &cp);
        const float c2p = cp * cp - sp * sp;
        const float s2p = 2.f * sp * cp;
#pragma unroll
        for (int zt = 0; zt < 2; ++zt) {
            const int z = zb + zt * 16 + (l & 15);
            out[(0 * XY_N + xy) * Z_N + z] = -A_CONST * (acc[0][zt][r] + acc[2][zt][r] * c2p);
            out[(1 * XY_N + xy) * Z_N + z] = -A_CONST * acc[2][zt][r] * s2p;
            out[(2 * XY_N + xy) * Z_N + z] = -2.f * A_CONST * acc[1][zt][r] * cp;
        }
    }
}

// ===========================================================================
// Fallback path (proven in R7): f32 vector kernel, handles any out_size/ws_size.
// ===========================================================================
#define OUT_F32_REAL    0
#define OUT_BF16_PLANAR 1
#define OUT_F32_PAIR    2

__global__ __launch_bounds__(256) void kern_build(
    const float* __restrict__ abbr,
    const float* __restrict__ theta,
    const float* __restrict__ U,
    float2* __restrict__ kern)
{
    int idx = blockIdx.x * blockDim.x + threadIdx.x;
    if (idx >= T_N * Z_N) return;
    int z = idx & (Z_N - 1);
    int t = idx >> 7;
    float th = theta[t];
    float w;
    if (t == 0)              w = 0.5f * (theta[1] - theta[0]);
    else if (t == T_N - 1)   w = 0.5f * (theta[T_N - 1] - theta[T_N - 2]);
    else                     w = 0.5f * (theta[t + 1] - theta[t - 1]);
    float ct  = cosf(th);
    float ang = abbr[t] - U[z] * ct;
    float s, c;
    sincosf(ang, &s, &c);
    kern[idx] = make_float2(c * w, s * w);
}

template <bool PRECOMP, int MODE>
__global__ __launch_bounds__(256) void psf_main(
    const float* __restrict__ F0, const float* __restrict__ F1,
    const float* __restrict__ F2, const float* __restrict__ Phi,
    const float2* __restrict__ kern, const float* __restrict__ abbr,
    const float* __restrict__ theta, const float* __restrict__ U,
    void* __restrict__ outv)
{
    __shared__ float flds[T_N * 24];
    __shared__ float ct_s[T_N];
    __shared__ float ear_s[T_N];
    __shared__ float eai_s[T_N];

    const int z   = threadIdx.x;
    const int ty  = threadIdx.y;
    const int tid = ty * 128 + z;
    const int xy0 = blockIdx.x * 8;

    if constexpr (!PRECOMP) {
        for (int t = tid; t < T_N; t += 256) {
            float th = theta[t];
            float w;
            if (t == 0)              w = 0.5f * (theta[1] - theta[0]);
            else if (t == T_N - 1)   w = 0.5f * (theta[T_N - 1] - theta[T_N - 2]);
            else                     w = 0.5f * (theta[t + 1] - theta[t - 1]);
            ct_s[t] = cosf(th);
            float s, c;
            sincosf(abbr[t], &s, &c);
            ear_s[t] = c * w;
            eai_s[t] = s * w;
        }
    }
    for (int li = tid; li < T_N * 24; li += 256) {
        int t  = li % T_N;
        int rc = li / T_N;
        int r  = rc & 7;
        int c  = rc >> 3;
        const float* __restrict__ F = (c == 0) ? F0 : (c == 1) ? F1 : F2;
        flds[t * 24 + c * 8 + r] = F[(xy0 + r) * T_N + t];
    }
    __syncthreads();

    const float Uz = U[z];
    float a0re[4] = {0,0,0,0}, a0im[4] = {0,0,0,0};
    float a1re[4] = {0,0,0,0}, a1im[4] = {0,0,0,0};
    float a2re[4] = {0,0,0,0}, a2im[4] = {0,0,0,0};
    const int rbase = ty * 4;

    for (int t = 0; t < T_N; ++t) {
        float2 k;
        if constexpr (PRECOMP) {
            k = kern[t * Z_N + z];
        } else {
            float ang = Uz * ct_s[t];
            float cs = __cosf(ang), sn = __sinf(ang);
            float er = ear_s[t], ei = eai_s[t];
            k.x = er * cs + ei * sn;
            k.y = ei * cs - er * sn;
        }
        float4 f0 = *(const float4*)&flds[t * 24 + 0 * 8 + rbase];
        float4 f1 = *(const float4*)&flds[t * 24 + 1 * 8 + rbase];
        float4 f2 = *(const float4*)&flds[t * 24 + 2 * 8 + rbase];
        a0re[0]+=f0.x*k.x; a0im[0]+=f0.x*k.y; a0re[1]+=f0.y*k.x; a0im[1]+=f0.y*k.y;
        a0re[2]+=f0.z*k.x; a0im[2]+=f0.z*k.y; a0re[3]+=f0.w*k.x; a0im[3]+=f0.w*k.y;
        a1re[0]+=f1.x*k.x; a1im[0]+=f1.x*k.y; a1re[1]+=f1.y*k.x; a1im[1]+=f1.y*k.y;
        a1re[2]+=f1.z*k.x; a1im[2]+=f1.z*k.y; a1re[3]+=f1.w*k.x; a1im[3]+=f1.w*k.y;
        a2re[0]+=f2.x*k.x; a2im[0]+=f2.x*k.y; a2re[1]+=f2.y*k.x; a2im[1]+=f2.y*k.y;
        a2re[2]+=f2.z*k.x; a2im[2]+=f2.z*k.y; a2re[3]+=f2.w*k.x; a2im[3]+=f2.w*k.y;
    }

#pragma unroll
    for (int r = 0; r < 4; ++r) {
        int xy = xy0 + rbase + r;
        float p = Phi[xy];
        float sp, cp;
        sincosf(p, &sp, &cp);
        float c2p = cp * cp - sp * sp;
        float s2p = 2.f * sp * cp;
        float ex_re = -A_CONST * (a0im[r] + a2im[r] * c2p);
        float ex_im =  A_CONST * (a0re[r] + a2re[r] * c2p);
        float ey_re = -A_CONST * a2im[r] * s2p;
        float ey_im =  A_CONST * a2re[r] * s2p;
        float ez_re = -2.f * A_CONST * a1re[r] * cp;
        float ez_im = -2.f * A_CONST * a1im[r] * cp;
        const int i0 = (0 * XY_N + xy) * Z_N + z;
        const int i1 = (1 * XY_N + xy) * Z_N + z;
        const int i2 = (2 * XY_N + xy) * Z_N + z;
        if constexpr (MODE == OUT_F32_REAL) {
            float* o = (float*)outv;
            o[i0] = ex_re; o[i1] = ey_re; o[i2] = ez_re;
        } else if constexpr (MODE == OUT_BF16_PLANAR) {
            __hip_bfloat16* o = (__hip_bfloat16*)outv;
            o[i0] = __float2bfloat16(ex_re); o[NCPLX + i0] = __float2bfloat16(ex_im);
            o[i1] = __float2bfloat16(ey_re); o[NCPLX + i1] = __float2bfloat16(ey_im);
            o[i2] = __float2bfloat16(ez_re); o[NCPLX + i2] = __float2bfloat16(ez_im);
        } else {
            float2* o = (float2*)outv;
            o[i0] = make_float2(ex_re, ex_im);
            o[i1] = make_float2(ey_re, ey_im);
            o[i2] = make_float2(ez_re, ez_im);
        }
    }
}

extern "C" void kernel_launch(void* const* d_in, const int* in_sizes, int n_in,
                              void* d_out, int out_size, void* d_ws, size_t ws_size,
                              hipStream_t stream) {
    const float* abbr  = (const float*)d_in[0];
    const float* F0    = (const float*)d_in[1];
    const float* F1    = (const float*)d_in[2];
    const float* F2    = (const float*)d_in[3];
    const float* Phi   = (const float*)d_in[4];
    const float* theta = (const float*)d_in[5];
    const float* U     = (const float*)d_in[6];

    const size_t kernBT_bytes = (size_t)2 * Z_N * K_PAD * sizeof(__hip_bfloat16); // 212992

    if (out_size == NCPLX && d_ws != nullptr && ws_size >= kernBT_bytes) {
        // Fast path: bf16 MFMA, real-part-only output (confirmed by R7/R9).
        __hip_bfloat16* kernBT = (__hip_bfloat16*)d_ws;
        kern_build_bf16<<<(2 * Z_N * K_PAD + 255) / 256, 256, 0, stream>>>(
            abbr, theta, U, kernBT);
        psf_mfma<<<XY_N / 16, 256, 0, stream>>>(F0, F1, F2, Phi, kernBT, (float*)d_out);
        return;
    }

    // Fallback: proven R7 f32 path.
    const size_t kern_bytes = (size_t)T_N * Z_N * sizeof(float2);
    const bool precomp = (d_ws != nullptr && ws_size >= kern_bytes);
    float2* kern = (float2*)d_ws;
    dim3 blk(128, 2, 1);
    if (precomp)
        kern_build<<<(T_N * Z_N + 255) / 256, 256, 0, stream>>>(abbr, theta, U, kern);

    int mode;
    if (out_size == NCPLX)          mode = OUT_F32_REAL;
    else if (out_size == 2 * NCPLX) mode = OUT_BF16_PLANAR;
    else if (out_size > 2 * NCPLX)  mode = OUT_F32_PAIR;
    else                            mode = OUT_F32_REAL;

    #define LAUNCH(P, M) psf_main<P, M><<<XY_N / 8, blk, 0, stream>>>( \
        F0, F1, F2, Phi, kern, abbr, theta, U, d_out)
    if (precomp) {
        if (mode == OUT_F32_REAL)         LAUNCH(true,  OUT_F32_REAL);
        else if (mode == OUT_BF16_PLANAR) LAUNCH(true,  OUT_BF16_PLANAR);
        else                              LAUNCH(true,  OUT_F32_PAIR);
    } else {
        if (mode == OUT_F32_REAL)         LAUNCH(false, OUT_F32_REAL);
        else if (mode == OUT_BF16_PLANAR) LAUNCH(false, OUT_BF16_PLANAR);
        else                              LAUNCH(false, OUT_F32_PAIR);
    }
    #undef LAUNCH
}

// Round 13
// 147.177 us; speedup vs baseline: 1.1102x; 1.1102x over previous
//
#include <hip/hip_runtime.h>
#include <hip/hip_bf16.h>
#include <math.h>

// Problem constants (match reference setup_inputs)
#define T_N   400      // NTHETA
#define KS    64       // K per step
#define NSTEP 7        // ceil(400/64)
#define K_PAD (KS * NSTEP)   // 448, B zero-padded
#define Z_N   128      // NZ
#define XY_N  16384    // NX*NY
#define NCPLX (3 * XY_N * Z_N)          // 6291456 = confirmed out_size (f32, real part)
#define A_CONST 5.905249382768714f      // pi / 0.532

typedef short  bf16x8 __attribute__((ext_vector_type(8)));
typedef float  f32x4  __attribute__((ext_vector_type(4)));

static __device__ __forceinline__ short f2bf(float f) {
    __hip_bfloat16 h = __float2bfloat16(f);
    return *reinterpret_cast<short*>(&h);
}
static __device__ __forceinline__ bf16x8 cvt8(f32x4 lo, f32x4 hi) {
    bf16x8 a;
    a[0] = f2bf(lo[0]); a[1] = f2bf(lo[1]); a[2] = f2bf(lo[2]); a[3] = f2bf(lo[3]);
    a[4] = f2bf(hi[0]); a[5] = f2bf(hi[1]); a[6] = f2bf(hi[2]); a[7] = f2bf(hi[3]);
    return a;
}

// ---------------------------------------------------------------------------
// Build B in ws: kernBT[p][z][k] bf16 (K_PAD=448); p=0: w*cos(ang), p=1: w*sin,
// ang = abbr[k] - U[z]*cos(theta[k]); k in [400,448) -> 0.
// Size: 2*128*448*2B = 229376 B.
// ---------------------------------------------------------------------------
__global__ __launch_bounds__(256) void kern_build_bf16(
    const float* __restrict__ abbr,
    const float* __restrict__ theta,
    const float* __restrict__ U,
    __hip_bfloat16* __restrict__ kernBT)
{
    int idx = blockIdx.x * 256 + threadIdx.x;    // (p*128 + z)*K_PAD + k
    if (idx >= 2 * Z_N * K_PAD) return;
    int k  = idx % K_PAD;
    int pz = idx / K_PAD;
    int z  = pz & 127;
    int p  = pz >> 7;

    float val = 0.f;
    if (k < T_N) {
        float th = theta[k];
        float w;
        if (k == 0)            w = 0.5f * (theta[1] - theta[0]);
        else if (k == T_N - 1) w = 0.5f * (theta[T_N - 1] - theta[T_N - 2]);
        else                   w = 0.5f * (theta[k + 1] - theta[k - 1]);
        float ang = abbr[k] - U[z] * cosf(th);
        val = w * ((p == 0) ? cosf(ang) : sinf(ang));
    }
    kernBT[idx] = __float2bfloat16(val);
}

// ---------------------------------------------------------------------------
// MFMA main v3 (R12 post-mortem: address-divergent A loads were the shared
// bottleneck). A staged via global_load_lds (coalesced 256B/row spans) into
// 24KB dbuf LDS with both-sides XOR swizzle (linear LDS dest, pre-swizzled
// global source chunk = sl ^ (row&7), same XOR on ds_read). B direct from
// L1/L2 (229KB, shared by all blocks). 2-phase: B-loads first, stage-next,
// ds_read+cvt, 12 MFMA, one __syncthreads (vmcnt drain) per k-step.
// Frags: A lane l: row=l&15, k=(l>>4)*8+0..7 | B lane l: k=(l>>4)*8, col=l&15
// C: col(z)=l&15, row(xy)=(l>>4)*4+reg.
// ---------------------------------------------------------------------------
#define GLOAD16(gp, loff)                                                   \
    __builtin_amdgcn_global_load_lds(                                       \
        (const __attribute__((address_space(1))) void*)(gp),                \
        (__attribute__((address_space(3))) void*)((char*)&As[0][0][0][0] + (loff)), \
        16, 0, 0)

__global__ __launch_bounds__(256, 4) void psf_mfma(
    const float* __restrict__ F0,
    const float* __restrict__ F1,
    const float* __restrict__ F2,
    const float* __restrict__ Phi,
    const __hip_bfloat16* __restrict__ kernBT,
    float* __restrict__ out)
{
    __shared__ float As[2][3][16][KS];   // [buf][comp][row][k] f32, 24576 B

    const int t    = threadIdx.x;
    const int l    = t & 63;
    const int wave = t >> 6;
    const int R    = blockIdx.x << 4;    // 16 rows per block
    const int zb   = wave << 5;          // 32 z per wave

    // --- staging coords (thread t -> row, 16B slot; source pre-swizzled) ---
    const int sr  = t >> 4;              // 0..15
    const int sl  = t & 15;
    const int skc = sl ^ (sr & 7);       // global 16B-chunk for this slot
    const size_t g_row = (size_t)(R + sr) * T_N;
    const int wbase = wave * 1024;       // wave-uniform LDS byte base (4 rows x 256B)

    // --- compute coords ---
    const int rr   = l & 15;             // fragment row
    const int g    = l >> 4;             // k-subgroup (0..3)
    const int xswz = (rr & 7) << 4;      // read-side XOR
    const int zc   = l & 15;             // B column lane

    f32x4 acc[3][2];
#pragma unroll
    for (int c = 0; c < 3; ++c)
#pragma unroll
        for (int zt = 0; zt < 2; ++zt) acc[c][zt] = (f32x4){0.f, 0.f, 0.f, 0.f};

    // --- prologue: stage k-step 0 into buf 0 ---
    {
        int gk = skc * 4;                            // < 64, always valid
        GLOAD16(F0 + g_row + gk, 0 * 12288 + 0 * 4096 + wbase);
        GLOAD16(F1 + g_row + gk, 0 * 12288 + 1 * 4096 + wbase);
        GLOAD16(F2 + g_row + gk, 0 * 12288 + 2 * 4096 + wbase);
    }
    __syncthreads();                                 // drains vmcnt(0)

    int buf = 0;
#pragma unroll 1
    for (int ks = 0; ks < NSTEP; ++ks) {
        const int kb = ks * KS;

        // 1) B loads first (L1-hot) so their waits don't drain the stage
        bf16x8 Bf[2][2][2];                          // [p][ztile][ksub]
#pragma unroll
        for (int p = 0; p < 2; ++p)
#pragma unroll
            for (int zt = 0; zt < 2; ++zt)
#pragma unroll
                for (int s = 0; s < 2; ++s)
                    Bf[p][zt][s] = *(const bf16x8*)(
                        kernBT + (size_t)(p * Z_N + zb + zt * 16 + zc) * K_PAD
                               + kb + s * 32 + g * 8);

        // 2) stage next k-step (async, in flight through compute)
        if (ks + 1 < NSTEP) {
            int gk = kb + KS + skc * 4;
            if (gk >= T_N) gk = 0;                   // tail: garbage x B=0
            const int nb = (buf ^ 1) * 12288;
            GLOAD16(F0 + g_row + gk, nb + 0 * 4096 + wbase);
            GLOAD16(F1 + g_row + gk, nb + 1 * 4096 + wbase);
            GLOAD16(F2 + g_row + gk, nb + 2 * 4096 + wbase);
        }

        // 3) A fragments from LDS (swizzled ds_read_b128 pairs + cvt)
        bf16x8 Af[3][2];
        const char* cb = (const char*)&As[0][0][0][0] + buf * 12288;
#pragma unroll
        for (int c = 0; c < 3; ++c)
#pragma unroll
            for (int s = 0; s < 2; ++s) {
                const int L = rr * 256 + s * 128 + g * 32;
                f32x4 lo = *(const f32x4*)(cb + c * 4096 + (L ^ xswz));
                f32x4 hi = *(const f32x4*)(cb + c * 4096 + ((L + 16) ^ xswz));
                Af[c][s] = cvt8(lo, hi);
            }

        // 4) 12 MFMAs: comp0 (F0 x im), comp1 (F1 x re), comp2 (F2 x im)
#pragma unroll
        for (int c = 0; c < 3; ++c) {
            const int p = (c == 1) ? 0 : 1;
#pragma unroll
            for (int zt = 0; zt < 2; ++zt) {
                acc[c][zt] = __builtin_amdgcn_mfma_f32_16x16x32_bf16(
                    Af[c][0], Bf[p][zt][0], acc[c][zt], 0, 0, 0);
                acc[c][zt] = __builtin_amdgcn_mfma_f32_16x16x32_bf16(
                    Af[c][1], Bf[p][zt][1], acc[c][zt], 0, 0, 0);
            }
        }

        __syncthreads();                             // stage complete + LDS safe
        buf ^= 1;
    }

    // --- Epilogue: Re(Ex) = -A*(I0im + I2im*cos2p); Re(Ey) = -A*I2im*sin2p;
    //               Re(Ez) = -2A*I1re*cosp ---
    const int xyb = R + (g << 2);
#pragma unroll
    for (int r = 0; r < 4; ++r) {
        const int xy = xyb + r;
        float ph = Phi[xy];
        float sp, cp;
        sincosf(ph, &sp, &cp);
        const float c2p = cp * cp - sp * sp;
        const float s2p = 2.f * sp * cp;
#pragma unroll
        for (int zt = 0; zt < 2; ++zt) {
            const int z = zb + zt * 16 + (l & 15);
            out[(0 * XY_N + xy) * Z_N + z] = -A_CONST * (acc[0][zt][r] + acc[2][zt][r] * c2p);
            out[(1 * XY_N + xy) * Z_N + z] = -A_CONST * acc[2][zt][r] * s2p;
            out[(2 * XY_N + xy) * Z_N + z] = -2.f * A_CONST * acc[1][zt][r] * cp;
        }
    }
}

// ===========================================================================
// Fallback path (proven in R7): f32 vector kernel, handles any out_size/ws_size.
// ===========================================================================
#define OUT_F32_REAL    0
#define OUT_BF16_PLANAR 1
#define OUT_F32_PAIR    2

__global__ __launch_bounds__(256) void kern_build(
    const float* __restrict__ abbr,
    const float* __restrict__ theta,
    const float* __restrict__ U,
    float2* __restrict__ kern)
{
    int idx = blockIdx.x * blockDim.x + threadIdx.x;
    if (idx >= T_N * Z_N) return;
    int z = idx & (Z_N - 1);
    int t = idx >> 7;
    float th = theta[t];
    float w;
    if (t == 0)              w = 0.5f * (theta[1] - theta[0]);
    else if (t == T_N - 1)   w = 0.5f * (theta[T_N - 1] - theta[T_N - 2]);
    else                     w = 0.5f * (theta[t + 1] - theta[t - 1]);
    float ct  = cosf(th);
    float ang = abbr[t] - U[z] * ct;
    float s, c;
    sincosf(ang, &s, &c);
    kern[idx] = make_float2(c * w, s * w);
}

template <bool PRECOMP, int MODE>
__global__ __launch_bounds__(256) void psf_main(
    const float* __restrict__ F0, const float* __restrict__ F1,
    const float* __restrict__ F2, const float* __restrict__ Phi,
    const float2* __restrict__ kern, const float* __restrict__ abbr,
    const float* __restrict__ theta, const float* __restrict__ U,
    void* __restrict__ outv)
{
    __shared__ float flds[T_N * 24];
    __shared__ float ct_s[T_N];
    __shared__ float ear_s[T_N];
    __shared__ float eai_s[T_N];

    const int z   = threadIdx.x;
    const int ty  = threadIdx.y;
    const int tid = ty * 128 + z;
    const int xy0 = blockIdx.x * 8;

    if constexpr (!PRECOMP) {
        for (int t = tid; t < T_N; t += 256) {
            float th = theta[t];
            float w;
            if (t == 0)              w = 0.5f * (theta[1] - theta[0]);
            else if (t == T_N - 1)   w = 0.5f * (theta[T_N - 1] - theta[T_N - 2]);
            else                     w = 0.5f * (theta[t + 1] - theta[t - 1]);
            ct_s[t] = cosf(th);
            float s, c;
            sincosf(abbr[t], &s, &c);
            ear_s[t] = c * w;
            eai_s[t] = s * w;
        }
    }
    for (int li = tid; li < T_N * 24; li += 256) {
        int t  = li % T_N;
        int rc = li / T_N;
        int r  = rc & 7;
        int c  = rc >> 3;
        const float* __restrict__ F = (c == 0) ? F0 : (c == 1) ? F1 : F2;
        flds[t * 24 + c * 8 + r] = F[(xy0 + r) * T_N + t];
    }
    __syncthreads();

    const float Uz = U[z];
    float a0re[4] = {0,0,0,0}, a0im[4] = {0,0,0,0};
    float a1re[4] = {0,0,0,0}, a1im[4] = {0,0,0,0};
    float a2re[4] = {0,0,0,0}, a2im[4] = {0,0,0,0};
    const int rbase = ty * 4;

    for (int t = 0; t < T_N; ++t) {
        float2 k;
        if constexpr (PRECOMP) {
            k = kern[t * Z_N + z];
        } else {
            float ang = Uz * ct_s[t];
            float cs = __cosf(ang), sn = __sinf(ang);
            float er = ear_s[t], ei = eai_s[t];
            k.x = er * cs + ei * sn;
            k.y = ei * cs - er * sn;
        }
        float4 f0 = *(const float4*)&flds[t * 24 + 0 * 8 + rbase];
        float4 f1 = *(const float4*)&flds[t * 24 + 1 * 8 + rbase];
        float4 f2 = *(const float4*)&flds[t * 24 + 2 * 8 + rbase];
        a0re[0]+=f0.x*k.x; a0im[0]+=f0.x*k.y; a0re[1]+=f0.y*k.x; a0im[1]+=f0.y*k.y;
        a0re[2]+=f0.z*k.x; a0im[2]+=f0.z*k.y; a0re[3]+=f0.w*k.x; a0im[3]+=f0.w*k.y;
        a1re[0]+=f1.x*k.x; a1im[0]+=f1.x*k.y; a1re[1]+=f1.y*k.x; a1im[1]+=f1.y*k.y;
        a1re[2]+=f1.z*k.x; a1im[2]+=f1.z*k.y; a1re[3]+=f1.w*k.x; a1im[3]+=f1.w*k.y;
        a2re[0]+=f2.x*k.x; a2im[0]+=f2.x*k.y; a2re[1]+=f2.y*k.x; a2im[1]+=f2.y*k.y;
        a2re[2]+=f2.z*k.x; a2im[2]+=f2.z*k.y; a2re[3]+=f2.w*k.x; a2im[3]+=f2.w*k.y;
    }

#pragma unroll
    for (int r = 0; r < 4; ++r) {
        int xy = xy0 + rbase + r;
        float p = Phi[xy];
        float sp, cp;
        sincosf(p, &sp, &cp);
        float c2p = cp * cp - sp * sp;
        float s2p = 2.f * sp * cp;
        float ex_re = -A_CONST * (a0im[r] + a2im[r] * c2p);
        float ex_im =  A_CONST * (a0re[r] + a2re[r] * c2p);
        float ey_re = -A_CONST * a2im[r] * s2p;
        float ey_im =  A_CONST * a2re[r] * s2p;
        float ez_re = -2.f * A_CONST * a1re[r] * cp;
        float ez_im = -2.f * A_CONST * a1im[r] * cp;
        const int i0 = (0 * XY_N + xy) * Z_N + z;
        const int i1 = (1 * XY_N + xy) * Z_N + z;
        const int i2 = (2 * XY_N + xy) * Z_N + z;
        if constexpr (MODE == OUT_F32_REAL) {
            float* o = (float*)outv;
            o[i0] = ex_re; o[i1] = ey_re; o[i2] = ez_re;
        } else if constexpr (MODE == OUT_BF16_PLANAR) {
            __hip_bfloat16* o = (__hip_bfloat16*)outv;
            o[i0] = __float2bfloat16(ex_re); o[NCPLX + i0] = __float2bfloat16(ex_im);
            o[i1] = __float2bfloat16(ey_re); o[NCPLX + i1] = __float2bfloat16(ey_im);
            o[i2] = __float2bfloat16(ez_re); o[NCPLX + i2] = __float2bfloat16(ez_im);
        } else {
            float2* o = (float2*)outv;
            o[i0] = make_float2(ex_re, ex_im);
            o[i1] = make_float2(ey_re, ey_im);
            o[i2] = make_float2(ez_re, ez_im);
        }
    }
}

extern "C" void kernel_launch(void* const* d_in, const int* in_sizes, int n_in,
                              void* d_out, int out_size, void* d_ws, size_t ws_size,
                              hipStream_t stream) {
    const float* abbr  = (const float*)d_in[0];
    const float* F0    = (const float*)d_in[1];
    const float* F1    = (const float*)d_in[2];
    const float* F2    = (const float*)d_in[3];
    const float* Phi   = (const float*)d_in[4];
    const float* theta = (const float*)d_in[5];
    const float* U     = (const float*)d_in[6];

    const size_t kernBT_bytes = (size_t)2 * Z_N * K_PAD * sizeof(__hip_bfloat16); // 229376

    if (out_size == NCPLX && d_ws != nullptr && ws_size >= kernBT_bytes) {
        // Fast path: bf16 MFMA with LDS-staged A (global_load_lds + XOR swizzle).
        __hip_bfloat16* kernBT = (__hip_bfloat16*)d_ws;
        kern_build_bf16<<<(2 * Z_N * K_PAD + 255) / 256, 256, 0, stream>>>(
            abbr, theta, U, kernBT);
        psf_mfma<<<XY_N / 16, 256, 0, stream>>>(F0, F1, F2, Phi, kernBT, (float*)d_out);
        return;
    }

    // Fallback: proven R7 f32 path.
    const size_t kern_bytes = (size_t)T_N * Z_N * sizeof(float2);
    const bool precomp = (d_ws != nullptr && ws_size >= kern_bytes);
    float2* kern = (float2*)d_ws;
    dim3 blk(128, 2, 1);
    if (precomp)
        kern_build<<<(T_N * Z_N + 255) / 256, 256, 0, stream>>>(abbr, theta, U, kern);

    int mode;
    if (out_size == NCPLX)          mode = OUT_F32_REAL;
    else if (out_size == 2 * NCPLX) mode = OUT_BF16_PLANAR;
    else if (out_size > 2 * NCPLX)  mode = OUT_F32_PAIR;
    else                            mode = OUT_F32_REAL;

    #define LAUNCH(P, M) psf_main<P, M><<<XY_N / 8, blk, 0, stream>>>( \
        F0, F1, F2, Phi, kern, abbr, theta, U, d_out)
    if (precomp) {
        if (mode == OUT_F32_REAL)         LAUNCH(true,  OUT_F32_REAL);
        else if (mode == OUT_BF16_PLANAR) LAUNCH(true,  OUT_BF16_PLANAR);
        else                              LAUNCH(true,  OUT_F32_PAIR);
    } else {
        if (mode == OUT_F32_REAL)         LAUNCH(false, OUT_F32_REAL);
        else if (mode == OUT_BF16_PLANAR) LAUNCH(false, OUT_BF16_PLANAR);
        else                              LAUNCH(false, OUT_F32_PAIR);
    }
    #undef LAUNCH
}